// Round 9
// baseline (40.921 us; speedup 1.0000x reference)
//
#include <hip/hip_runtime.h>

typedef __bf16 v8bf __attribute__((ext_vector_type(8)));
typedef __bf16 v4bf __attribute__((ext_vector_type(4)));
typedef float f32x4 __attribute__((ext_vector_type(4)));

#define NB 8
#define MM 128
#define DD 64

// ---------------- Kernel A: row/col/diag sums (-> bf16 V) + weight repack ----------------
// grid 1024; XCD-aligned: n = b & 7, i = b >> 3
__global__ __launch_bounds__(256) void k_prep(
        const float* __restrict__ x, const float* __restrict__ coefs,
        __bf16* __restrict__ V, __bf16* __restrict__ WT, __bf16* __restrict__ Wc,
        __bf16* __restrict__ C1T, __bf16* __restrict__ C2T) {
    int b = blockIdx.x, t = threadIdx.x;

    if (b < 144) {                       // WT: 192*192 = 36864
        int e = b * 256 + t;
        int sg = e / 192, k = e % 192;
        int g = sg >> 6, s = sg & 63, kg = k >> 6, d = k & 63;
        int plane;
        if (g == 0)      plane = (kg == 0) ? 4 : (kg == 1) ? 11 : 12;
        else if (g == 1) plane = (kg == 0) ? 3 : (kg == 1) ? 9 : 10;
        else             plane = (kg == 0) ? 2 : (kg == 1) ? 7 : 6;
        WT[e] = (__bf16)coefs[d * 960 + s * 15 + plane];
    } else if (b < 240) {                // Wc: 192*128 = 24576
        int e = (b - 144) * 256 + t;
        int sg = e >> 7, k = e & 127;
        int g = sg >> 6, s = sg & 63, d = k & 63;
        float v = 0.f;
        if (g == 0)      v = coefs[d * 960 + s * 15 + (k < 64 ? 13 : 14)];
        else if (g == 2) v = coefs[d * 960 + s * 15 + (k < 64 ? 5 : 8)];
        Wc[e] = (__bf16)v;
    } else if (b < 272) {                // C1T/C2T: 2*4096
        int e = (b - 240) * 256 + t;
        int m = e >> 12, q = e & 4095, s = q >> 6, d = q & 63;
        __bf16 v = (__bf16)coefs[d * 960 + s * 15 + m];
        if (m == 0) C1T[s * 64 + d] = v;
        else        C2T[s * 64 + d] = v;
    }

    int n = b & 7, i = b >> 3;
    int r = n * 128 + i;
    const float* xn = x + (size_t)n * (MM * MM * DD);
    int d4 = (t & 15) << 2, c = t >> 4;

    f32x4 ar = {0.f, 0.f, 0.f, 0.f}, ac = {0.f, 0.f, 0.f, 0.f};
    for (int j = c; j < MM; j += 16) {
        ar += *(const f32x4*)(xn + (i * MM + j) * DD + d4);
        ac += *(const f32x4*)(xn + (j * MM + i) * DD + d4);
    }
    __shared__ float red_r[16][64], red_c[16][64];
    *(f32x4*)&red_r[c][d4] = ar;
    *(f32x4*)&red_c[c][d4] = ac;
    __syncthreads();
    if (t < 64) {
        float rs = 0.f, cc = 0.f;
        #pragma unroll
        for (int g = 0; g < 16; ++g) { rs += red_r[g][t]; cc += red_c[g][t]; }
        float dg = xn[(i * MM + i) * DD + t];
        V[(size_t)r * 192 + t]       = (__bf16)dg;
        V[(size_t)r * 192 + 64 + t]  = (__bf16)cc;
        V[(size_t)r * 192 + 128 + t] = (__bf16)rs;
    }
}

// ---------------- Kernel B: projection GEMM ----------------
__global__ __launch_bounds__(256) void k_proj(
        const __bf16* __restrict__ V, const __bf16* __restrict__ WT,
        const __bf16* __restrict__ Wc, const float* __restrict__ bias,
        const float* __restrict__ diag_bias,
        float* __restrict__ F, float* __restrict__ G, float* __restrict__ Dd) {
    __shared__ __bf16 Vs[64][200];
    __shared__ __bf16 Ws[64][200];
    __shared__ float red[8][64];
    __shared__ float sdsa[128];
    __shared__ float corrL[64];

    int bx = blockIdx.x;
    int mt = bx / 3, g = bx % 3;
    int r0 = mt * 64, n = mt >> 1;
    int t = threadIdx.x;

    #pragma unroll
    for (int c = 0; c < 6; ++c) {
        int v = c * 256 + t;
        int rr = v / 24, kb = (v % 24) * 8;
        *(v8bf*)&Vs[rr][kb] = *(const v8bf*)&V[(size_t)(r0 + rr) * 192 + kb];
    }
    #pragma unroll
    for (int c = 0; c < 6; ++c) {
        int v = c * 256 + t;
        int rr = v / 24, kb = (v % 24) * 8;
        *(v8bf*)&Ws[rr][kb] = *(const v8bf*)&WT[(size_t)(g * 64 + rr) * 192 + kb];
    }

    if (g != 1) {
        int d = t & 63, rg = t >> 6;
        float psd = 0.f, psa = 0.f;
        const __bf16* Vn = V + (size_t)(n * 128) * 192;
        for (int rr = rg * 32; rr < rg * 32 + 32; ++rr) {
            psd += (float)Vn[rr * 192 + d];
            psa += (float)Vn[rr * 192 + 128 + d];
        }
        red[rg][d] = psd;
        red[4 + rg][d] = psa;
    }
    __syncthreads();

    if (g != 1) {
        if (t < 128) {
            int half = t >> 6, d = t & 63;
            sdsa[t] = red[half * 4 + 0][d] + red[half * 4 + 1][d]
                    + red[half * 4 + 2][d] + red[half * 4 + 3][d];
        }
    } else if (t < 64) {
        corrL[t] = 0.f;
    }
    __syncthreads();

    if (g != 1) {
        int w = t >> 6, l = t & 63;
        int s = w * 16 + (l & 15), kc = l >> 4;
        const __bf16* wc = Wc + (size_t)(g * 64 + s) * 128 + kc * 32;
        float p = 0.f;
        #pragma unroll
        for (int kk = 0; kk < 32; ++kk) p += sdsa[kc * 32 + kk] * (float)wc[kk];
        p += __shfl_xor(p, 16);
        p += __shfl_xor(p, 32);
        if (l < 16) corrL[s] = p + (g == 0 ? bias[s] : diag_bias[s]);
    }

    int w = t >> 6, l = t & 63, lr = l & 15, hi = l >> 4;
    int arow = w * 16 + lr;
    f32x4 acc[4];
    #pragma unroll
    for (int st = 0; st < 4; ++st) acc[st] = (f32x4){0.f, 0.f, 0.f, 0.f};
    #pragma unroll
    for (int kk = 0; kk < 6; ++kk) {
        int ko = kk * 32 + hi * 8;
        v8bf a = *(const v8bf*)&Vs[arow][ko];
        #pragma unroll
        for (int st = 0; st < 4; ++st) {
            v8bf bb = *(const v8bf*)&Ws[st * 16 + lr][ko];
            acc[st] = __builtin_amdgcn_mfma_f32_16x16x32_bf16(a, bb, acc[st], 0, 0, 0);
        }
    }
    __syncthreads();

    float* O = (g == 0) ? F : (g == 1) ? G : Dd;
    #pragma unroll
    for (int st = 0; st < 4; ++st) {
        int s = st * 16 + lr;
        float cv = corrL[s];
        #pragma unroll
        for (int q = 0; q < 4; ++q) {
            int rr = w * 16 + hi * 4 + q;
            O[(size_t)(r0 + rr) * 64 + s] = acc[st][q] + cv;
        }
    }
}

// ---------------- Kernel C: main MFMA kernel, LDS-free (per-lane direct fragments) ----------------
// grid 1536 = 8 n (low 3 bits) x 192 tile-units; all x/coef reads L2-resident per XCD.
__global__ __launch_bounds__(256) void k_main(
        const float* __restrict__ x, const float* __restrict__ mask,
        const float* __restrict__ F, const float* __restrict__ G,
        const float* __restrict__ Dd, const __bf16* __restrict__ C1T,
        const __bf16* __restrict__ C2T, float* __restrict__ out) {
    int bid = blockIdx.x;
    int n = bid & 7;
    int b = bid >> 3;
    int i, h; bool mir;
    if (b < 128) { i = b; h = b >> 6; mir = false; }
    else         { i = b - 128; h = 1; mir = true; }
    int j0 = h << 6;
    int tid = threadIdx.x;

    int w = tid >> 6, l = tid & 63;
    int lr = l & 15, hi = l >> 4;
    int arow = w * 16 + lr;               // this lane's pair row within the 64-tile

    const float* xn = x + (size_t)n * (MM * MM * DD);
    const float* aid = xn + ((size_t)i * MM + j0 + arow) * DD;        // x[n, i, j0+arow, :]
    const float* atd = xn + ((size_t)(j0 + arow) * MM + i) * DD;      // x[n, j0+arow, i, :]

    // ---- load fragments directly to registers ----
    v8bf a1f[2], a2f[2], b1f[4][2], b2f[4][2];
    #pragma unroll
    for (int kk = 0; kk < 2; ++kk) {
        int ko = kk * 32 + hi * 8;
        f32x4 p0 = *(const f32x4*)(aid + ko);
        f32x4 p1 = *(const f32x4*)(aid + ko + 4);
        a1f[kk] = (v8bf){(__bf16)p0[0], (__bf16)p0[1], (__bf16)p0[2], (__bf16)p0[3],
                         (__bf16)p1[0], (__bf16)p1[1], (__bf16)p1[2], (__bf16)p1[3]};
        f32x4 q0 = *(const f32x4*)(atd + ko);
        f32x4 q1 = *(const f32x4*)(atd + ko + 4);
        a2f[kk] = (v8bf){(__bf16)q0[0], (__bf16)q0[1], (__bf16)q0[2], (__bf16)q0[3],
                         (__bf16)q1[0], (__bf16)q1[1], (__bf16)q1[2], (__bf16)q1[3]};
    }
    #pragma unroll
    for (int st = 0; st < 4; ++st) {
        int srow = st * 16 + lr;
        #pragma unroll
        for (int kk = 0; kk < 2; ++kk) {
            int ko = kk * 32 + hi * 8;
            b1f[st][kk] = *(const v8bf*)(C1T + (size_t)srow * 64 + ko);
            b2f[st][kk] = *(const v8bf*)(C2T + (size_t)srow * 64 + ko);
        }
    }

    f32x4 acc1[4], acc2[4];
    #pragma unroll
    for (int st = 0; st < 4; ++st) { acc1[st] = (f32x4){0.f,0.f,0.f,0.f}; acc2[st] = (f32x4){0.f,0.f,0.f,0.f}; }

    #pragma unroll
    for (int kk = 0; kk < 2; ++kk) {
        #pragma unroll
        for (int st = 0; st < 4; ++st) {
            acc1[st] = __builtin_amdgcn_mfma_f32_16x16x32_bf16(a1f[kk], b1f[st][kk], acc1[st], 0, 0, 0);
            acc1[st] = __builtin_amdgcn_mfma_f32_16x16x32_bf16(a2f[kk], b2f[st][kk], acc1[st], 0, 0, 0);
            if (mir) {
                acc2[st] = __builtin_amdgcn_mfma_f32_16x16x32_bf16(a2f[kk], b1f[st][kk], acc2[st], 0, 0, 0);
                acc2[st] = __builtin_amdgcn_mfma_f32_16x16x32_bf16(a1f[kk], b2f[st][kk], acc2[st], 0, 0, 0);
            }
        }
    }

    // ---- epilogue (same as R8): C/D layout col = lane&15, row = hi*4+q ----
    int base_i = n * MM + i;
    const float* Fp = F + base_i * 64;
    const float* Dp = Dd + base_i * 64;
    const float* Gn = G + n * MM * 64;
    const float* mrow = mask + (size_t)base_i * MM + j0;
    float* outp = out + ((size_t)base_i * MM + j0) * 64;

    #pragma unroll
    for (int st = 0; st < 4; ++st) {
        int s = st * 16 + lr;
        float Fv = Fp[s];
        float Dv = Dp[s];
        #pragma unroll
        for (int q = 0; q < 4; ++q) {
            int r = w * 16 + hi * 4 + q;
            int j = j0 + r;
            float v = acc1[st][q] + Fv + Gn[j * 64 + s];
            if (i == j) v += Dv;
            v = v > 0.f ? v : 0.01f * v;
            v *= mrow[r];
            outp[(size_t)r * 64 + s] = v;
        }
    }

    if (mir) {
        const float* Gi = G + (n * MM + i) * 64;
        #pragma unroll
        for (int st = 0; st < 4; ++st) {
            int s = st * 16 + lr;
            float Gv = Gi[s];
            #pragma unroll
            for (int q = 0; q < 4; ++q) {
                int r = w * 16 + hi * 4 + q;
                int j = j0 + r;
                int row = n * MM + j;
                float v = acc2[st][q] + F[row * 64 + s] + Gv;
                v = v > 0.f ? v : 0.01f * v;
                v *= mask[(size_t)row * MM + i];
                out[((size_t)row * MM + i) * 64 + s] = v;
            }
        }
    }
}

extern "C" void kernel_launch(void* const* d_in, const int* in_sizes, int n_in,
                              void* d_out, int out_size, void* d_ws, size_t ws_size,
                              hipStream_t stream) {
    const float* x = (const float*)d_in[0];
    // d_in[1] = nobj (unused: config 's' -> no rescale)
    const float* mask = (const float*)d_in[2];
    const float* coefs = (const float*)d_in[3];
    const float* bias = (const float*)d_in[4];
    const float* diag_bias = (const float*)d_in[5];
    float* out = (float*)d_out;

    float* w0 = (float*)d_ws;
    float* F = w0;                          // 65536 f32
    float* G = w0 + 65536;                  // 65536 f32
    float* Dd = w0 + 131072;                // 65536 f32
    __bf16* V   = (__bf16*)(w0 + 196608);   // 1024*192 bf16
    __bf16* WT  = (__bf16*)(w0 + 294912);   // 192*192 bf16
    __bf16* Wc  = (__bf16*)(w0 + 313344);   // 192*128 bf16
    __bf16* C1T = (__bf16*)(w0 + 325632);   // 4096 bf16
    __bf16* C2T = (__bf16*)(w0 + 327680);   // 4096 bf16

    k_prep<<<dim3(1024), dim3(256), 0, stream>>>(x, coefs, V, WT, Wc, C1T, C2T);
    k_proj<<<dim3(48), dim3(256), 0, stream>>>(V, WT, Wc, bias, diag_bias, F, G, Dd);
    k_main<<<dim3(1536), dim3(256), 0, stream>>>(x, mask, F, G, Dd, C1T, C2T, out);
}

// Round 10
// 30.005 us; speedup vs baseline: 1.3638x; 1.3638x over previous
//
#include <hip/hip_runtime.h>

typedef __bf16 v8bf __attribute__((ext_vector_type(8)));
typedef __bf16 v4bf __attribute__((ext_vector_type(4)));
typedef float f32x4 __attribute__((ext_vector_type(4)));

#define NB 8
#define MM 128
#define DD 64

// ---------------- Kernel A: row/col/diag sums (-> bf16 V) + weight repack ----------------
// grid 1024; XCD-aligned: n = b & 7, i = b >> 3
__global__ __launch_bounds__(256) void k_prep(
        const float* __restrict__ x, const float* __restrict__ coefs,
        __bf16* __restrict__ V, __bf16* __restrict__ WT, __bf16* __restrict__ Wc,
        __bf16* __restrict__ C1T, __bf16* __restrict__ C2T) {
    int b = blockIdx.x, t = threadIdx.x;

    if (b < 144) {                       // WT: 192*192 = 36864
        int e = b * 256 + t;
        int sg = e / 192, k = e % 192;
        int g = sg >> 6, s = sg & 63, kg = k >> 6, d = k & 63;
        int plane;
        if (g == 0)      plane = (kg == 0) ? 4 : (kg == 1) ? 11 : 12;
        else if (g == 1) plane = (kg == 0) ? 3 : (kg == 1) ? 9 : 10;
        else             plane = (kg == 0) ? 2 : (kg == 1) ? 7 : 6;
        WT[e] = (__bf16)coefs[d * 960 + s * 15 + plane];
    } else if (b < 240) {                // Wc: 192*128 = 24576
        int e = (b - 144) * 256 + t;
        int sg = e >> 7, k = e & 127;
        int g = sg >> 6, s = sg & 63, d = k & 63;
        float v = 0.f;
        if (g == 0)      v = coefs[d * 960 + s * 15 + (k < 64 ? 13 : 14)];
        else if (g == 2) v = coefs[d * 960 + s * 15 + (k < 64 ? 5 : 8)];
        Wc[e] = (__bf16)v;
    } else if (b < 272) {                // C1T/C2T: 2*4096
        int e = (b - 240) * 256 + t;
        int m = e >> 12, q = e & 4095, s = q >> 6, d = q & 63;
        __bf16 v = (__bf16)coefs[d * 960 + s * 15 + m];
        if (m == 0) C1T[s * 64 + d] = v;
        else        C2T[s * 64 + d] = v;
    }

    int n = b & 7, i = b >> 3;
    int r = n * 128 + i;
    const float* xn = x + (size_t)n * (MM * MM * DD);
    int d4 = (t & 15) << 2, c = t >> 4;

    f32x4 ar = {0.f, 0.f, 0.f, 0.f}, ac = {0.f, 0.f, 0.f, 0.f};
    for (int j = c; j < MM; j += 16) {
        ar += *(const f32x4*)(xn + (i * MM + j) * DD + d4);
        ac += *(const f32x4*)(xn + (j * MM + i) * DD + d4);
    }
    __shared__ float red_r[16][64], red_c[16][64];
    *(f32x4*)&red_r[c][d4] = ar;
    *(f32x4*)&red_c[c][d4] = ac;
    __syncthreads();
    if (t < 64) {
        float rs = 0.f, cc = 0.f;
        #pragma unroll
        for (int g = 0; g < 16; ++g) { rs += red_r[g][t]; cc += red_c[g][t]; }
        float dg = xn[(i * MM + i) * DD + t];
        V[(size_t)r * 192 + t]       = (__bf16)dg;
        V[(size_t)r * 192 + 64 + t]  = (__bf16)cc;
        V[(size_t)r * 192 + 128 + t] = (__bf16)rs;
    }
}

// ---------------- Kernel B: projection GEMM ----------------
__global__ __launch_bounds__(256) void k_proj(
        const __bf16* __restrict__ V, const __bf16* __restrict__ WT,
        const __bf16* __restrict__ Wc, const float* __restrict__ bias,
        const float* __restrict__ diag_bias,
        float* __restrict__ F, float* __restrict__ G, float* __restrict__ Dd) {
    __shared__ __bf16 Vs[64][200];
    __shared__ __bf16 Ws[64][200];
    __shared__ float red[8][64];
    __shared__ float sdsa[128];
    __shared__ float corrL[64];

    int bx = blockIdx.x;
    int mt = bx / 3, g = bx % 3;
    int r0 = mt * 64, n = mt >> 1;
    int t = threadIdx.x;

    #pragma unroll
    for (int c = 0; c < 6; ++c) {
        int v = c * 256 + t;
        int rr = v / 24, kb = (v % 24) * 8;
        *(v8bf*)&Vs[rr][kb] = *(const v8bf*)&V[(size_t)(r0 + rr) * 192 + kb];
    }
    #pragma unroll
    for (int c = 0; c < 6; ++c) {
        int v = c * 256 + t;
        int rr = v / 24, kb = (v % 24) * 8;
        *(v8bf*)&Ws[rr][kb] = *(const v8bf*)&WT[(size_t)(g * 64 + rr) * 192 + kb];
    }

    if (g != 1) {
        int d = t & 63, rg = t >> 6;
        float psd = 0.f, psa = 0.f;
        const __bf16* Vn = V + (size_t)(n * 128) * 192;
        for (int rr = rg * 32; rr < rg * 32 + 32; ++rr) {
            psd += (float)Vn[rr * 192 + d];
            psa += (float)Vn[rr * 192 + 128 + d];
        }
        red[rg][d] = psd;
        red[4 + rg][d] = psa;
    }
    __syncthreads();

    if (g != 1) {
        if (t < 128) {
            int half = t >> 6, d = t & 63;
            sdsa[t] = red[half * 4 + 0][d] + red[half * 4 + 1][d]
                    + red[half * 4 + 2][d] + red[half * 4 + 3][d];
        }
    } else if (t < 64) {
        corrL[t] = 0.f;
    }
    __syncthreads();

    if (g != 1) {
        int w = t >> 6, l = t & 63;
        int s = w * 16 + (l & 15), kc = l >> 4;
        const __bf16* wc = Wc + (size_t)(g * 64 + s) * 128 + kc * 32;
        float p = 0.f;
        #pragma unroll
        for (int kk = 0; kk < 32; ++kk) p += sdsa[kc * 32 + kk] * (float)wc[kk];
        p += __shfl_xor(p, 16);
        p += __shfl_xor(p, 32);
        if (l < 16) corrL[s] = p + (g == 0 ? bias[s] : diag_bias[s]);
    }

    int w = t >> 6, l = t & 63, lr = l & 15, hi = l >> 4;
    int arow = w * 16 + lr;
    f32x4 acc[4];
    #pragma unroll
    for (int st = 0; st < 4; ++st) acc[st] = (f32x4){0.f, 0.f, 0.f, 0.f};
    #pragma unroll
    for (int kk = 0; kk < 6; ++kk) {
        int ko = kk * 32 + hi * 8;
        v8bf a = *(const v8bf*)&Vs[arow][ko];
        #pragma unroll
        for (int st = 0; st < 4; ++st) {
            v8bf bb = *(const v8bf*)&Ws[st * 16 + lr][ko];
            acc[st] = __builtin_amdgcn_mfma_f32_16x16x32_bf16(a, bb, acc[st], 0, 0, 0);
        }
    }
    __syncthreads();

    float* O = (g == 0) ? F : (g == 1) ? G : Dd;
    #pragma unroll
    for (int st = 0; st < 4; ++st) {
        int s = st * 16 + lr;
        float cv = corrL[s];
        #pragma unroll
        for (int q = 0; q < 4; ++q) {
            int rr = w * 16 + hi * 4 + q;
            O[(size_t)(r0 + rr) * 64 + s] = acc[st][q] + cv;
        }
    }
}

// ---------------- Kernel C: main MFMA kernel, 2 tile-units/block, nt out stores ----------------
// grid 768 = 8 n (low 3 bits) x 96 unit-pairs; coefs staged once per block.
__global__ __launch_bounds__(256) void k_main(
        const float* __restrict__ x, const float* __restrict__ mask,
        const float* __restrict__ F, const float* __restrict__ G,
        const float* __restrict__ Dd, const __bf16* __restrict__ C1T,
        const __bf16* __restrict__ C2T, float* __restrict__ out) {
    __shared__ __bf16 Xs[64][72];
    __shared__ __bf16 XTs[64][72];
    __shared__ __bf16 C1s[64][72];
    __shared__ __bf16 C2s[64][72];

    int bid = blockIdx.x;
    int n = bid & 7;
    int u = bid >> 3;                 // 0..95
    int tid = threadIdx.x;

    const float* xn = x + (size_t)n * (MM * MM * DD);

    // stage coefs once
    #pragma unroll
    for (int c = 0; c < 4; ++c) {
        int v = c * 256 + tid;
        int s = v >> 4, d0 = (v & 15) << 2;
        *(v4bf*)&C1s[s][d0] = ((const v4bf*)C1T)[v];
        *(v4bf*)&C2s[s][d0] = ((const v4bf*)C2T)[v];
    }

    int w = tid >> 6, l = tid & 63;
    int lr = l & 15, hi = l >> 4;
    int arow = w * 16 + lr;

    for (int half = 0; half < 2; ++half) {
        int b = u * 2 + half;         // 0..191
        int i, h; bool mir;
        if (b < 128) { i = b; h = b >> 6; mir = false; }
        else         { i = b - 128; h = 1; mir = true; }
        int j0 = h << 6;

        __syncthreads();              // prior unit's LDS reads done (no-op first iter)

        const float* xid = xn + ((size_t)i * MM + j0) * DD;
        #pragma unroll
        for (int c = 0; c < 4; ++c) {
            int v = c * 256 + tid;
            float4 f4 = ((const float4*)xid)[v];
            int r = v >> 4, d0 = (v & 15) << 2;
            v4bf bb = {(__bf16)f4.x, (__bf16)f4.y, (__bf16)f4.z, (__bf16)f4.w};
            *(v4bf*)&Xs[r][d0] = bb;
        }
        #pragma unroll
        for (int c = 0; c < 4; ++c) {
            int v = c * 256 + tid;
            int r = v >> 4, d0 = (v & 15) << 2;
            float4 f4 = *(const float4*)(xn + ((size_t)(j0 + r) * MM + i) * DD + d0);
            v4bf bb = {(__bf16)f4.x, (__bf16)f4.y, (__bf16)f4.z, (__bf16)f4.w};
            *(v4bf*)&XTs[r][d0] = bb;
        }
        __syncthreads();

        f32x4 acc1[4], acc2[4];
        #pragma unroll
        for (int st = 0; st < 4; ++st) { acc1[st] = (f32x4){0.f,0.f,0.f,0.f}; acc2[st] = (f32x4){0.f,0.f,0.f,0.f}; }

        #pragma unroll
        for (int kk = 0; kk < 2; ++kk) {
            int ko = kk * 32 + hi * 8;
            v8bf a1 = *(const v8bf*)&Xs[arow][ko];
            v8bf a2 = *(const v8bf*)&XTs[arow][ko];
            #pragma unroll
            for (int st = 0; st < 4; ++st) {
                v8bf b1 = *(const v8bf*)&C1s[st * 16 + lr][ko];
                v8bf b2 = *(const v8bf*)&C2s[st * 16 + lr][ko];
                acc1[st] = __builtin_amdgcn_mfma_f32_16x16x32_bf16(a1, b1, acc1[st], 0, 0, 0);
                acc1[st] = __builtin_amdgcn_mfma_f32_16x16x32_bf16(a2, b2, acc1[st], 0, 0, 0);
                if (mir) {
                    acc2[st] = __builtin_amdgcn_mfma_f32_16x16x32_bf16(a2, b1, acc2[st], 0, 0, 0);
                    acc2[st] = __builtin_amdgcn_mfma_f32_16x16x32_bf16(a1, b2, acc2[st], 0, 0, 0);
                }
            }
        }

        int base_i = n * MM + i;
        const float* Fp = F + base_i * 64;
        const float* Dp = Dd + base_i * 64;
        const float* Gn = G + n * MM * 64;
        const float* mrow = mask + (size_t)base_i * MM + j0;
        float* outp = out + ((size_t)base_i * MM + j0) * 64;

        #pragma unroll
        for (int st = 0; st < 4; ++st) {
            int s = st * 16 + lr;
            float Fv = Fp[s];
            float Dv = Dp[s];
            #pragma unroll
            for (int q = 0; q < 4; ++q) {
                int r = w * 16 + hi * 4 + q;
                int j = j0 + r;
                float v = acc1[st][q] + Fv + Gn[j * 64 + s];
                if (i == j) v += Dv;
                v = v > 0.f ? v : 0.01f * v;
                v *= mrow[r];
                __builtin_nontemporal_store(v, &outp[(size_t)r * 64 + s]);
            }
        }

        if (mir) {
            const float* Gi = G + (n * MM + i) * 64;
            #pragma unroll
            for (int st = 0; st < 4; ++st) {
                int s = st * 16 + lr;
                float Gv = Gi[s];
                #pragma unroll
                for (int q = 0; q < 4; ++q) {
                    int r = w * 16 + hi * 4 + q;
                    int j = j0 + r;
                    int row = n * MM + j;
                    float v = acc2[st][q] + F[row * 64 + s] + Gv;
                    v = v > 0.f ? v : 0.01f * v;
                    v *= mask[(size_t)row * MM + i];
                    __builtin_nontemporal_store(v, &out[((size_t)row * MM + i) * 64 + s]);
                }
            }
        }
    }
}

extern "C" void kernel_launch(void* const* d_in, const int* in_sizes, int n_in,
                              void* d_out, int out_size, void* d_ws, size_t ws_size,
                              hipStream_t stream) {
    const float* x = (const float*)d_in[0];
    // d_in[1] = nobj (unused: config 's' -> no rescale)
    const float* mask = (const float*)d_in[2];
    const float* coefs = (const float*)d_in[3];
    const float* bias = (const float*)d_in[4];
    const float* diag_bias = (const float*)d_in[5];
    float* out = (float*)d_out;

    float* w0 = (float*)d_ws;
    float* F = w0;                          // 65536 f32
    float* G = w0 + 65536;                  // 65536 f32
    float* Dd = w0 + 131072;                // 65536 f32
    __bf16* V   = (__bf16*)(w0 + 196608);   // 1024*192 bf16
    __bf16* WT  = (__bf16*)(w0 + 294912);   // 192*192 bf16
    __bf16* Wc  = (__bf16*)(w0 + 313344);   // 192*128 bf16
    __bf16* C1T = (__bf16*)(w0 + 325632);   // 4096 bf16
    __bf16* C2T = (__bf16*)(w0 + 327680);   // 4096 bf16

    k_prep<<<dim3(1024), dim3(256), 0, stream>>>(x, coefs, V, WT, Wc, C1T, C2T);
    k_proj<<<dim3(48), dim3(256), 0, stream>>>(V, WT, Wc, bias, diag_bias, F, G, Dd);
    k_main<<<dim3(768), dim3(256), 0, stream>>>(x, mask, F, G, Dd, C1T, C2T, out);
}

// Round 11
// 29.545 us; speedup vs baseline: 1.3850x; 1.0156x over previous
//
#include <hip/hip_runtime.h>

typedef __bf16 v8bf __attribute__((ext_vector_type(8)));
typedef __bf16 v4bf __attribute__((ext_vector_type(4)));
typedef float f32x4 __attribute__((ext_vector_type(4)));

#define NB 8
#define MM 128
#define DD 64

// ---------------- Kernel A: split row/col sums (-> bf16 V) + weight repack ----------------
// grid 2048; blocks 0..1023 row-work, 1024..2047 col-work. XCD-aligned: n = b & 7.
// V[r][k]: k 0..63 = diag, 64..127 = colsum, 128..191 = rowsum (bf16), r = n*128+i
__global__ __launch_bounds__(256) void k_prep(
        const float* __restrict__ x, const float* __restrict__ coefs,
        __bf16* __restrict__ V, __bf16* __restrict__ WT, __bf16* __restrict__ Wc,
        __bf16* __restrict__ C1T, __bf16* __restrict__ C2T) {
    int b = blockIdx.x, t = threadIdx.x;

    // ---- weight repack folded into first 272 blocks ----
    if (b < 144) {                       // WT: 192*192 = 36864
        int e = b * 256 + t;
        int sg = e / 192, k = e % 192;
        int g = sg >> 6, s = sg & 63, kg = k >> 6, d = k & 63;
        int plane;
        if (g == 0)      plane = (kg == 0) ? 4 : (kg == 1) ? 11 : 12;
        else if (g == 1) plane = (kg == 0) ? 3 : (kg == 1) ? 9 : 10;
        else             plane = (kg == 0) ? 2 : (kg == 1) ? 7 : 6;
        WT[e] = (__bf16)coefs[d * 960 + s * 15 + plane];
    } else if (b < 240) {                // Wc: 192*128 = 24576
        int e = (b - 144) * 256 + t;
        int sg = e >> 7, k = e & 127;
        int g = sg >> 6, s = sg & 63, d = k & 63;
        float v = 0.f;
        if (g == 0)      v = coefs[d * 960 + s * 15 + (k < 64 ? 13 : 14)];
        else if (g == 2) v = coefs[d * 960 + s * 15 + (k < 64 ? 5 : 8)];
        Wc[e] = (__bf16)v;
    } else if (b < 272) {                // C1T/C2T: 2*4096
        int e = (b - 240) * 256 + t;
        int m = e >> 12, q = e & 4095, s = q >> 6, d = q & 63;
        __bf16 v = (__bf16)coefs[d * 960 + s * 15 + m];
        if (m == 0) C1T[s * 64 + d] = v;
        else        C2T[s * 64 + d] = v;
    }

    bool isRow = b < 1024;
    int bb = isRow ? b : b - 1024;
    int n = bb & 7, i = bb >> 3;
    int r = n * 128 + i;
    const float* xn = x + (size_t)n * (MM * MM * DD);
    int jA = t >> 4, dq = t & 15;
    int d4 = dq << 2;

    __shared__ float red[16][64];

    f32x4 acc = {0.f, 0.f, 0.f, 0.f};
    if (isRow) {
        const float* xrow = xn + (size_t)i * MM * DD;
        #pragma unroll
        for (int sl = 0; sl < 8; ++sl) {
            int j = jA + sl * 16;
            acc += *(const f32x4*)(xrow + j * DD + d4);
        }
    } else {
        #pragma unroll
        for (int sl = 0; sl < 8; ++sl) {
            int j = jA + sl * 16;
            acc += *(const f32x4*)(xn + ((size_t)j * MM + i) * DD + d4);
        }
    }
    *(f32x4*)&red[jA][d4] = acc;
    __syncthreads();

    if (t < 64) {
        float s = 0.f;
        #pragma unroll
        for (int g = 0; g < 16; ++g) s += red[g][t];
        if (isRow) {
            V[(size_t)r * 192 + 128 + t] = (__bf16)s;                     // rowsum
            V[(size_t)r * 192 + t] = (__bf16)xn[((size_t)i * MM + i) * DD + t];  // diag
        } else {
            V[(size_t)r * 192 + 64 + t] = (__bf16)s;                      // colsum
        }
    }
}

// ---------------- Kernel B: projection GEMM, wide (192 blocks, 16-row tiles) ----------------
// grid 192 = mt(64 tiles of 16 rows) * 3 g; block 256 (4 waves, one per 16-col slab)
__global__ __launch_bounds__(256) void k_proj(
        const __bf16* __restrict__ V, const __bf16* __restrict__ WT,
        const __bf16* __restrict__ Wc, const float* __restrict__ bias,
        const float* __restrict__ diag_bias,
        float* __restrict__ F, float* __restrict__ G, float* __restrict__ Dd) {
    __shared__ __bf16 Vs[16][200];
    __shared__ __bf16 Ws[64][200];
    __shared__ float red[8][64];
    __shared__ float sdsaL[128];
    __shared__ float corrL[64];

    int bx = blockIdx.x;
    int mt = bx / 3, g = bx % 3;
    int r0 = mt * 16, n = mt >> 3;
    int t = threadIdx.x;

    // stage W tile (64 rows x 192)
    #pragma unroll
    for (int c = 0; c < 6; ++c) {
        int v = c * 256 + t;
        int rr = v / 24, kb = (v % 24) * 8;
        *(v8bf*)&Ws[rr][kb] = *(const v8bf*)&WT[(size_t)(g * 64 + rr) * 192 + kb];
    }
    // stage V tile (16 rows x 192 = 384 chunks)
    #pragma unroll
    for (int c = 0; c < 2; ++c) {
        int v = c * 256 + t;
        if (v < 384) {
            int rr = v / 24, kb = (v % 24) * 8;
            *(v8bf*)&Vs[rr][kb] = *(const v8bf*)&V[(size_t)(r0 + rr) * 192 + kb];
        }
    }

    // sd/sa reduce over this n's 128 V rows (g != 1 only)
    if (g != 1) {
        int d = t & 63, rg = t >> 6;
        float psd = 0.f, psa = 0.f;
        const __bf16* Vn = V + (size_t)(n * 128) * 192;
        for (int rr = rg * 32; rr < rg * 32 + 32; ++rr) {
            psd += (float)Vn[rr * 192 + d];
            psa += (float)Vn[rr * 192 + 128 + d];
        }
        red[rg][d] = psd;
        red[4 + rg][d] = psa;
    }
    __syncthreads();

    if (g != 1) {
        if (t < 128) {
            int half = t >> 6, d = t & 63;
            sdsaL[t] = red[half * 4 + 0][d] + red[half * 4 + 1][d]
                     + red[half * 4 + 2][d] + red[half * 4 + 3][d];
        }
    } else if (t < 64) {
        corrL[t] = 0.f;
    }
    __syncthreads();

    if (g != 1) {
        int w = t >> 6, l = t & 63;
        int s = w * 16 + (l & 15), kc = l >> 4;
        const __bf16* wc = Wc + (size_t)(g * 64 + s) * 128 + kc * 32;
        float p = 0.f;
        #pragma unroll
        for (int kk = 0; kk < 32; ++kk) p += sdsaL[kc * 32 + kk] * (float)wc[kk];
        p += __shfl_xor(p, 16);
        p += __shfl_xor(p, 32);
        if (l < 16) corrL[s] = p + (g == 0 ? bias[s] : diag_bias[s]);
    }

    // MFMA: wave w -> out cols w*16..w*16+15, rows r0..r0+15, K = 192
    int w = t >> 6, l = t & 63, lr = l & 15, hi = l >> 4;
    f32x4 acc = (f32x4){0.f, 0.f, 0.f, 0.f};
    #pragma unroll
    for (int kk = 0; kk < 6; ++kk) {
        int ko = kk * 32 + hi * 8;
        v8bf a = *(const v8bf*)&Vs[lr][ko];
        v8bf bb = *(const v8bf*)&Ws[w * 16 + lr][ko];
        acc = __builtin_amdgcn_mfma_f32_16x16x32_bf16(a, bb, acc, 0, 0, 0);
    }
    __syncthreads();

    float* O = (g == 0) ? F : (g == 1) ? G : Dd;
    int s = w * 16 + lr;
    float cv = corrL[s];
    #pragma unroll
    for (int q = 0; q < 4; ++q) {
        int rr = hi * 4 + q;
        O[(size_t)(r0 + rr) * 64 + s] = acc[q] + cv;
    }
}

// ---------------- Kernel C: main MFMA kernel, 2 tile-units/block, nt out stores ----------------
// grid 768 = 8 n (low 3 bits) x 96 unit-pairs; coefs staged once per block.
__global__ __launch_bounds__(256) void k_main(
        const float* __restrict__ x, const float* __restrict__ mask,
        const float* __restrict__ F, const float* __restrict__ G,
        const float* __restrict__ Dd, const __bf16* __restrict__ C1T,
        const __bf16* __restrict__ C2T, float* __restrict__ out) {
    __shared__ __bf16 Xs[64][72];
    __shared__ __bf16 XTs[64][72];
    __shared__ __bf16 C1s[64][72];
    __shared__ __bf16 C2s[64][72];

    int bid = blockIdx.x;
    int n = bid & 7;
    int u = bid >> 3;                 // 0..95
    int tid = threadIdx.x;

    const float* xn = x + (size_t)n * (MM * MM * DD);

    #pragma unroll
    for (int c = 0; c < 4; ++c) {
        int v = c * 256 + tid;
        int s = v >> 4, d0 = (v & 15) << 2;
        *(v4bf*)&C1s[s][d0] = ((const v4bf*)C1T)[v];
        *(v4bf*)&C2s[s][d0] = ((const v4bf*)C2T)[v];
    }

    int w = tid >> 6, l = tid & 63;
    int lr = l & 15, hi = l >> 4;
    int arow = w * 16 + lr;

    for (int half = 0; half < 2; ++half) {
        int b = u * 2 + half;         // 0..191
        int i, h; bool mir;
        if (b < 128) { i = b; h = b >> 6; mir = false; }
        else         { i = b - 128; h = 1; mir = true; }
        int j0 = h << 6;

        __syncthreads();

        const float* xid = xn + ((size_t)i * MM + j0) * DD;
        #pragma unroll
        for (int c = 0; c < 4; ++c) {
            int v = c * 256 + tid;
            float4 f4 = ((const float4*)xid)[v];
            int r = v >> 4, d0 = (v & 15) << 2;
            v4bf bb = {(__bf16)f4.x, (__bf16)f4.y, (__bf16)f4.z, (__bf16)f4.w};
            *(v4bf*)&Xs[r][d0] = bb;
        }
        #pragma unroll
        for (int c = 0; c < 4; ++c) {
            int v = c * 256 + tid;
            int r = v >> 4, d0 = (v & 15) << 2;
            float4 f4 = *(const float4*)(xn + ((size_t)(j0 + r) * MM + i) * DD + d0);
            v4bf bb = {(__bf16)f4.x, (__bf16)f4.y, (__bf16)f4.z, (__bf16)f4.w};
            *(v4bf*)&XTs[r][d0] = bb;
        }
        __syncthreads();

        f32x4 acc1[4], acc2[4];
        #pragma unroll
        for (int st = 0; st < 4; ++st) { acc1[st] = (f32x4){0.f,0.f,0.f,0.f}; acc2[st] = (f32x4){0.f,0.f,0.f,0.f}; }

        #pragma unroll
        for (int kk = 0; kk < 2; ++kk) {
            int ko = kk * 32 + hi * 8;
            v8bf a1 = *(const v8bf*)&Xs[arow][ko];
            v8bf a2 = *(const v8bf*)&XTs[arow][ko];
            #pragma unroll
            for (int st = 0; st < 4; ++st) {
                v8bf b1 = *(const v8bf*)&C1s[st * 16 + lr][ko];
                v8bf b2 = *(const v8bf*)&C2s[st * 16 + lr][ko];
                acc1[st] = __builtin_amdgcn_mfma_f32_16x16x32_bf16(a1, b1, acc1[st], 0, 0, 0);
                acc1[st] = __builtin_amdgcn_mfma_f32_16x16x32_bf16(a2, b2, acc1[st], 0, 0, 0);
                if (mir) {
                    acc2[st] = __builtin_amdgcn_mfma_f32_16x16x32_bf16(a2, b1, acc2[st], 0, 0, 0);
                    acc2[st] = __builtin_amdgcn_mfma_f32_16x16x32_bf16(a1, b2, acc2[st], 0, 0, 0);
                }
            }
        }

        int base_i = n * MM + i;
        const float* Fp = F + base_i * 64;
        const float* Dp = Dd + base_i * 64;
        const float* Gn = G + n * MM * 64;
        const float* mrow = mask + (size_t)base_i * MM + j0;
        float* outp = out + ((size_t)base_i * MM + j0) * 64;

        #pragma unroll
        for (int st = 0; st < 4; ++st) {
            int s = st * 16 + lr;
            float Fv = Fp[s];
            float Dv = Dp[s];
            #pragma unroll
            for (int q = 0; q < 4; ++q) {
                int r = w * 16 + hi * 4 + q;
                int j = j0 + r;
                float v = acc1[st][q] + Fv + Gn[j * 64 + s];
                if (i == j) v += Dv;
                v = v > 0.f ? v : 0.01f * v;
                v *= mrow[r];
                __builtin_nontemporal_store(v, &outp[(size_t)r * 64 + s]);
            }
        }

        if (mir) {
            const float* Gi = G + (n * MM + i) * 64;
            #pragma unroll
            for (int st = 0; st < 4; ++st) {
                int s = st * 16 + lr;
                float Gv = Gi[s];
                #pragma unroll
                for (int q = 0; q < 4; ++q) {
                    int r = w * 16 + hi * 4 + q;
                    int j = j0 + r;
                    int row = n * MM + j;
                    float v = acc2[st][q] + F[row * 64 + s] + Gv;
                    v = v > 0.f ? v : 0.01f * v;
                    v *= mask[(size_t)row * MM + i];
                    __builtin_nontemporal_store(v, &out[((size_t)row * MM + i) * 64 + s]);
                }
            }
        }
    }
}

extern "C" void kernel_launch(void* const* d_in, const int* in_sizes, int n_in,
                              void* d_out, int out_size, void* d_ws, size_t ws_size,
                              hipStream_t stream) {
    const float* x = (const float*)d_in[0];
    // d_in[1] = nobj (unused: config 's' -> no rescale)
    const float* mask = (const float*)d_in[2];
    const float* coefs = (const float*)d_in[3];
    const float* bias = (const float*)d_in[4];
    const float* diag_bias = (const float*)d_in[5];
    float* out = (float*)d_out;

    float* w0 = (float*)d_ws;
    float* F = w0;                          // 65536 f32
    float* G = w0 + 65536;                  // 65536 f32
    float* Dd = w0 + 131072;                // 65536 f32
    __bf16* V   = (__bf16*)(w0 + 196608);   // 1024*192 bf16
    __bf16* WT  = (__bf16*)(w0 + 294912);   // 192*192 bf16
    __bf16* Wc  = (__bf16*)(w0 + 313344);   // 192*128 bf16
    __bf16* C1T = (__bf16*)(w0 + 325632);   // 4096 bf16
    __bf16* C2T = (__bf16*)(w0 + 327680);   // 4096 bf16

    k_prep<<<dim3(2048), dim3(256), 0, stream>>>(x, coefs, V, WT, Wc, C1T, C2T);
    k_proj<<<dim3(192), dim3(256), 0, stream>>>(V, WT, Wc, bias, diag_bias, F, G, Dd);
    k_main<<<dim3(768), dim3(256), 0, stream>>>(x, mask, F, G, Dd, C1T, C2T, out);
}

// Round 14
// 29.519 us; speedup vs baseline: 1.3863x; 1.0009x over previous
//
#include <hip/hip_runtime.h>

typedef __bf16 v8bf __attribute__((ext_vector_type(8)));
typedef __bf16 v4bf __attribute__((ext_vector_type(4)));
typedef float f32x4 __attribute__((ext_vector_type(4)));

#define NB 8
#define MM 128
#define DD 64

// ---------------- Kernel A: split row/col sums (-> bf16 V) + weight repack ----------------
// grid 2048; blocks 0..1023 row-work, 1024..2047 col-work. XCD-aligned: n = b & 7.
// V[r][k]: k 0..63 = diag, 64..127 = colsum, 128..191 = rowsum (bf16), r = n*128+i
__global__ __launch_bounds__(256) void k_prep(
        const float* __restrict__ x, const float* __restrict__ coefs,
        __bf16* __restrict__ V, __bf16* __restrict__ WT, __bf16* __restrict__ Wc,
        __bf16* __restrict__ C1T, __bf16* __restrict__ C2T) {
    int b = blockIdx.x, t = threadIdx.x;

    // ---- weight repack folded into first 272 blocks ----
    if (b < 144) {                       // WT: 192*192 = 36864
        int e = b * 256 + t;
        int sg = e / 192, k = e % 192;
        int g = sg >> 6, s = sg & 63, kg = k >> 6, d = k & 63;
        int plane;
        if (g == 0)      plane = (kg == 0) ? 4 : (kg == 1) ? 11 : 12;
        else if (g == 1) plane = (kg == 0) ? 3 : (kg == 1) ? 9 : 10;
        else             plane = (kg == 0) ? 2 : (kg == 1) ? 7 : 6;
        WT[e] = (__bf16)coefs[d * 960 + s * 15 + plane];
    } else if (b < 240) {                // Wc: 192*128 = 24576
        int e = (b - 144) * 256 + t;
        int sg = e >> 7, k = e & 127;
        int g = sg >> 6, s = sg & 63, d = k & 63;
        float v = 0.f;
        if (g == 0)      v = coefs[d * 960 + s * 15 + (k < 64 ? 13 : 14)];
        else if (g == 2) v = coefs[d * 960 + s * 15 + (k < 64 ? 5 : 8)];
        Wc[e] = (__bf16)v;
    } else if (b < 272) {                // C1T/C2T: 2*4096
        int e = (b - 240) * 256 + t;
        int m = e >> 12, q = e & 4095, s = q >> 6, d = q & 63;
        __bf16 v = (__bf16)coefs[d * 960 + s * 15 + m];
        if (m == 0) C1T[s * 64 + d] = v;
        else        C2T[s * 64 + d] = v;
    }

    bool isRow = b < 1024;
    int bb = isRow ? b : b - 1024;
    int n = bb & 7, i = bb >> 3;
    int r = n * 128 + i;
    const float* xn = x + (size_t)n * (MM * MM * DD);
    int jA = t >> 4, dq = t & 15;
    int d4 = dq << 2;

    __shared__ float red[16][64];

    f32x4 acc = {0.f, 0.f, 0.f, 0.f};
    if (isRow) {
        const float* xrow = xn + (size_t)i * MM * DD;
        #pragma unroll
        for (int sl = 0; sl < 8; ++sl) {
            int j = jA + sl * 16;
            acc += *(const f32x4*)(xrow + j * DD + d4);
        }
    } else {
        #pragma unroll
        for (int sl = 0; sl < 8; ++sl) {
            int j = jA + sl * 16;
            acc += *(const f32x4*)(xn + ((size_t)j * MM + i) * DD + d4);
        }
    }
    *(f32x4*)&red[jA][d4] = acc;
    __syncthreads();

    if (t < 64) {
        float s = 0.f;
        #pragma unroll
        for (int g = 0; g < 16; ++g) s += red[g][t];
        if (isRow) {
            V[(size_t)r * 192 + 128 + t] = (__bf16)s;                     // rowsum
            V[(size_t)r * 192 + t] = (__bf16)xn[((size_t)i * MM + i) * DD + t];  // diag
        } else {
            V[(size_t)r * 192 + 64 + t] = (__bf16)s;                      // colsum
        }
    }
}

// ---------------- Kernel B: projection GEMM, wide (192 blocks, 16-row tiles) ----------------
// grid 192 = mt(64 tiles of 16 rows) * 3 g; block 256 (4 waves, one per 16-col slab)
__global__ __launch_bounds__(256) void k_proj(
        const __bf16* __restrict__ V, const __bf16* __restrict__ WT,
        const __bf16* __restrict__ Wc, const float* __restrict__ bias,
        const float* __restrict__ diag_bias,
        float* __restrict__ F, float* __restrict__ G, float* __restrict__ Dd) {
    __shared__ __bf16 Vs[16][200];
    __shared__ __bf16 Ws[64][200];
    __shared__ float red[8][64];
    __shared__ float sdsaL[128];
    __shared__ float corrL[64];

    int bx = blockIdx.x;
    int mt = bx / 3, g = bx % 3;
    int r0 = mt * 16, n = mt >> 3;
    int t = threadIdx.x;

    // stage W tile (64 rows x 192)
    #pragma unroll
    for (int c = 0; c < 6; ++c) {
        int v = c * 256 + t;
        int rr = v / 24, kb = (v % 24) * 8;
        *(v8bf*)&Ws[rr][kb] = *(const v8bf*)&WT[(size_t)(g * 64 + rr) * 192 + kb];
    }
    // stage V tile (16 rows x 192 = 384 chunks)
    #pragma unroll
    for (int c = 0; c < 2; ++c) {
        int v = c * 256 + t;
        if (v < 384) {
            int rr = v / 24, kb = (v % 24) * 8;
            *(v8bf*)&Vs[rr][kb] = *(const v8bf*)&V[(size_t)(r0 + rr) * 192 + kb];
        }
    }

    // sd/sa reduce over this n's 128 V rows (g != 1 only)
    if (g != 1) {
        int d = t & 63, rg = t >> 6;
        float psd = 0.f, psa = 0.f;
        const __bf16* Vn = V + (size_t)(n * 128) * 192;
        for (int rr = rg * 32; rr < rg * 32 + 32; ++rr) {
            psd += (float)Vn[rr * 192 + d];
            psa += (float)Vn[rr * 192 + 128 + d];
        }
        red[rg][d] = psd;
        red[4 + rg][d] = psa;
    }
    __syncthreads();

    if (g != 1) {
        if (t < 128) {
            int half = t >> 6, d = t & 63;
            sdsaL[t] = red[half * 4 + 0][d] + red[half * 4 + 1][d]
                     + red[half * 4 + 2][d] + red[half * 4 + 3][d];
        }
    } else if (t < 64) {
        corrL[t] = 0.f;
    }
    __syncthreads();

    if (g != 1) {
        int w = t >> 6, l = t & 63;
        int s = w * 16 + (l & 15), kc = l >> 4;
        const __bf16* wc = Wc + (size_t)(g * 64 + s) * 128 + kc * 32;
        float p = 0.f;
        #pragma unroll
        for (int kk = 0; kk < 32; ++kk) p += sdsaL[kc * 32 + kk] * (float)wc[kk];
        p += __shfl_xor(p, 16);
        p += __shfl_xor(p, 32);
        if (l < 16) corrL[s] = p + (g == 0 ? bias[s] : diag_bias[s]);
    }

    // MFMA: wave w -> out cols w*16..w*16+15, rows r0..r0+15, K = 192
    int w = t >> 6, l = t & 63, lr = l & 15, hi = l >> 4;
    f32x4 acc = (f32x4){0.f, 0.f, 0.f, 0.f};
    #pragma unroll
    for (int kk = 0; kk < 6; ++kk) {
        int ko = kk * 32 + hi * 8;
        v8bf a = *(const v8bf*)&Vs[lr][ko];
        v8bf bb = *(const v8bf*)&Ws[w * 16 + lr][ko];
        acc = __builtin_amdgcn_mfma_f32_16x16x32_bf16(a, bb, acc, 0, 0, 0);
    }
    __syncthreads();

    float* O = (g == 0) ? F : (g == 1) ? G : Dd;
    int s = w * 16 + lr;
    float cv = corrL[s];
    #pragma unroll
    for (int q = 0; q < 4; ++q) {
        int rr = hi * 4 + q;
        O[(size_t)(r0 + rr) * 64 + s] = acc[q] + cv;
    }
}

// ---------------- Kernel C: main MFMA kernel, 2 tile-units/block, nt out stores ----------------
// grid 768 = 8 n (low 3 bits) x 96 unit-pairs; coefs staged once per block.
__global__ __launch_bounds__(256) void k_main(
        const float* __restrict__ x, const float* __restrict__ mask,
        const float* __restrict__ F, const float* __restrict__ G,
        const float* __restrict__ Dd, const __bf16* __restrict__ C1T,
        const __bf16* __restrict__ C2T, float* __restrict__ out) {
    __shared__ __bf16 Xs[64][72];
    __shared__ __bf16 XTs[64][72];
    __shared__ __bf16 C1s[64][72];
    __shared__ __bf16 C2s[64][72];

    int bid = blockIdx.x;
    int n = bid & 7;
    int u = bid >> 3;                 // 0..95
    int tid = threadIdx.x;

    const float* xn = x + (size_t)n * (MM * MM * DD);

    #pragma unroll
    for (int c = 0; c < 4; ++c) {
        int v = c * 256 + tid;
        int s = v >> 4, d0 = (v & 15) << 2;
        *(v4bf*)&C1s[s][d0] = ((const v4bf*)C1T)[v];
        *(v4bf*)&C2s[s][d0] = ((const v4bf*)C2T)[v];
    }

    int w = tid >> 6, l = tid & 63;
    int lr = l & 15, hi = l >> 4;
    int arow = w * 16 + lr;

    for (int half = 0; half < 2; ++half) {
        int b = u * 2 + half;         // 0..191
        int i, h; bool mir;
        if (b < 128) { i = b; h = b >> 6; mir = false; }
        else         { i = b - 128; h = 1; mir = true; }
        int j0 = h << 6;

        __syncthreads();

        const float* xid = xn + ((size_t)i * MM + j0) * DD;
        #pragma unroll
        for (int c = 0; c < 4; ++c) {
            int v = c * 256 + tid;
            float4 f4 = ((const float4*)xid)[v];
            int r = v >> 4, d0 = (v & 15) << 2;
            v4bf bb = {(__bf16)f4.x, (__bf16)f4.y, (__bf16)f4.z, (__bf16)f4.w};
            *(v4bf*)&Xs[r][d0] = bb;
        }
        #pragma unroll
        for (int c = 0; c < 4; ++c) {
            int v = c * 256 + tid;
            int r = v >> 4, d0 = (v & 15) << 2;
            float4 f4 = *(const float4*)(xn + ((size_t)(j0 + r) * MM + i) * DD + d0);
            v4bf bb = {(__bf16)f4.x, (__bf16)f4.y, (__bf16)f4.z, (__bf16)f4.w};
            *(v4bf*)&XTs[r][d0] = bb;
        }
        __syncthreads();

        f32x4 acc1[4], acc2[4];
        #pragma unroll
        for (int st = 0; st < 4; ++st) { acc1[st] = (f32x4){0.f,0.f,0.f,0.f}; acc2[st] = (f32x4){0.f,0.f,0.f,0.f}; }

        #pragma unroll
        for (int kk = 0; kk < 2; ++kk) {
            int ko = kk * 32 + hi * 8;
            v8bf a1 = *(const v8bf*)&Xs[arow][ko];
            v8bf a2 = *(const v8bf*)&XTs[arow][ko];
            #pragma unroll
            for (int st = 0; st < 4; ++st) {
                v8bf b1 = *(const v8bf*)&C1s[st * 16 + lr][ko];
                v8bf b2 = *(const v8bf*)&C2s[st * 16 + lr][ko];
                acc1[st] = __builtin_amdgcn_mfma_f32_16x16x32_bf16(a1, b1, acc1[st], 0, 0, 0);
                acc1[st] = __builtin_amdgcn_mfma_f32_16x16x32_bf16(a2, b2, acc1[st], 0, 0, 0);
                if (mir) {
                    acc2[st] = __builtin_amdgcn_mfma_f32_16x16x32_bf16(a2, b1, acc2[st], 0, 0, 0);
                    acc2[st] = __builtin_amdgcn_mfma_f32_16x16x32_bf16(a1, b2, acc2[st], 0, 0, 0);
                }
            }
        }

        int base_i = n * MM + i;
        const float* Fp = F + base_i * 64;
        const float* Dp = Dd + base_i * 64;
        const float* Gn = G + n * MM * 64;
        const float* mrow = mask + (size_t)base_i * MM + j0;
        float* outp = out + ((size_t)base_i * MM + j0) * 64;

        #pragma unroll
        for (int st = 0; st < 4; ++st) {
            int s = st * 16 + lr;
            float Fv = Fp[s];
            float Dv = Dp[s];
            #pragma unroll
            for (int q = 0; q < 4; ++q) {
                int r = w * 16 + hi * 4 + q;
                int j = j0 + r;
                float v = acc1[st][q] + Fv + Gn[j * 64 + s];
                if (i == j) v += Dv;
                v = v > 0.f ? v : 0.01f * v;
                v *= mrow[r];
                __builtin_nontemporal_store(v, &outp[(size_t)r * 64 + s]);
            }
        }

        if (mir) {
            const float* Gi = G + (n * MM + i) * 64;
            #pragma unroll
            for (int st = 0; st < 4; ++st) {
                int s = st * 16 + lr;
                float Gv = Gi[s];
                #pragma unroll
                for (int q = 0; q < 4; ++q) {
                    int r = w * 16 + hi * 4 + q;
                    int j = j0 + r;
                    int row = n * MM + j;
                    float v = acc2[st][q] + F[row * 64 + s] + Gv;
                    v = v > 0.f ? v : 0.01f * v;
                    v *= mask[(size_t)row * MM + i];
                    __builtin_nontemporal_store(v, &out[((size_t)row * MM + i) * 64 + s]);
                }
            }
        }
    }
}

extern "C" void kernel_launch(void* const* d_in, const int* in_sizes, int n_in,
                              void* d_out, int out_size, void* d_ws, size_t ws_size,
                              hipStream_t stream) {
    const float* x = (const float*)d_in[0];
    // d_in[1] = nobj (unused: config 's' -> no rescale)
    const float* mask = (const float*)d_in[2];
    const float* coefs = (const float*)d_in[3];
    const float* bias = (const float*)d_in[4];
    const float* diag_bias = (const float*)d_in[5];
    float* out = (float*)d_out;

    float* w0 = (float*)d_ws;
    float* F = w0;                          // 65536 f32
    float* G = w0 + 65536;                  // 65536 f32
    float* Dd = w0 + 131072;                // 65536 f32
    __bf16* V   = (__bf16*)(w0 + 196608);   // 1024*192 bf16
    __bf16* WT  = (__bf16*)(w0 + 294912);   // 192*192 bf16
    __bf16* Wc  = (__bf16*)(w0 + 313344);   // 192*128 bf16
    __bf16* C1T = (__bf16*)(w0 + 325632);   // 4096 bf16
    __bf16* C2T = (__bf16*)(w0 + 327680);   // 4096 bf16

    k_prep<<<dim3(2048), dim3(256), 0, stream>>>(x, coefs, V, WT, Wc, C1T, C2T);
    k_proj<<<dim3(192), dim3(256), 0, stream>>>(V, WT, Wc, bias, diag_bias, F, G, Dd);
    k_main<<<dim3(768), dim3(256), 0, stream>>>(x, mask, F, G, Dd, C1T, C2T, out);
}